// Round 14
// baseline (322.043 us; speedup 1.0000x reference)
//
#include <hip/hip_runtime.h>
#include <hip/hip_fp16.h>

#define N_NODES 50000
#define N_EDGES 600000
#define N_GRAPHS 64
#define HID 128
#define OUT_C 32

#define N_SCAN_BLOCKS ((N_NODES + 255) / 256)   // 196
#define SCAN_FLAG 0x40000000

typedef __attribute__((ext_vector_type(8))) _Float16 half8;
typedef __attribute__((ext_vector_type(4))) float f32x4;

// ================= prep: zero {pooled,degi,bsum} + fp16 casts + graph boundaries ==========
#define ZERO_INTS (N_GRAPHS * 128 + N_NODES + N_SCAN_BLOCKS)   // pooled + degi + bsum

__global__ __launch_bounds__(256) void prep_kernel(
    const float* __restrict__ x, const int* __restrict__ batch,
    const float* __restrict__ W1l, const float* __restrict__ W1r,
    const float* __restrict__ W2l, const float* __restrict__ W2r,
    __half* __restrict__ xh, __half* __restrict__ Wt1, __half* __restrict__ Wt2,
    int* __restrict__ zero_base, int* __restrict__ gstart) {
    const int b = blockIdx.x;
    const int t = threadIdx.x;
    const int gtid = b * 256 + t;
    const int gsz = gridDim.x * 256;
    for (int i = gtid; i < ZERO_INTS; i += gsz) zero_base[i] = 0;

    // graph boundaries from sorted batch
    for (int i = gtid; i <= N_NODES; i += gsz) {
        if (i == 0) {
            int b1 = batch[0];
            for (int g = 0; g <= b1; ++g) gstart[g] = 0;
        } else if (i == N_NODES) {
            int b0 = batch[N_NODES - 1];
            for (int g = b0 + 1; g <= N_GRAPHS; ++g) gstart[g] = N_NODES;
        } else {
            int b0 = batch[i - 1], b1 = batch[i];
            for (int g = b0 + 1; g <= b1; ++g) gstart[g] = i;
        }
    }

    if (b < 16) {
        for (int i = gtid; i < 65536; i += 4096) {
            int which = i >> 15;
            int j = i & 32767;
            int n = j >> 8, k = j & 255;
            const float* Wl = which ? W2l : W1l;
            const float* Wr = which ? W2r : W1r;
            float a = (k < 128) ? Wl[n * 128 + k] : Wr[n * 128 + (k - 128)];
            (which ? Wt2 : Wt1)[j] = __float2half(a);
        }
    } else {
        int i = ((b - 16) * 256 + t) * 4;
        if (i < N_NODES * 128) {
            float4 v = *(const float4*)(x + i);
            __half2 a = __floats2half2_rn(v.x, v.y);
            __half2 c = __floats2half2_rn(v.z, v.w);
            uint2 st;
            st.x = *(const unsigned int*)&a;
            st.y = *(const unsigned int*)&c;
            *(uint2*)(xh + i) = st;
        }
    }
}

// ================= CSR: degrees =================
__global__ void deg_kernel(const int* __restrict__ dst, int* __restrict__ deg, int E) {
    int e = blockIdx.x * 256 + threadIdx.x;
    if (e < E) atomicAdd(&deg[dst[e]], 1);
}

// ================= CSR: single-dispatch scan (decoupled lookback); inits cursor ==========
__global__ __launch_bounds__(256) void scan_fused(
    const int* __restrict__ deg, int* __restrict__ bsum,
    int* __restrict__ rowptr, int* __restrict__ cursor, float* __restrict__ invdeg) {
    __shared__ int s[256];
    const int b = blockIdx.x;
    const int t = threadIdx.x;
    const int idx = b * 256 + t;
    const int v = (idx < N_NODES) ? deg[idx] : 0;
    s[t] = v;
    __syncthreads();
    for (int off = 1; off < 256; off <<= 1) {
        int u = (t >= off) ? s[t - off] : 0;
        __syncthreads();
        s[t] += u;
        __syncthreads();
    }
    const int incl = s[t];
    if (t == 255) atomicExch(&bsum[b], incl | SCAN_FLAG);

    int pv = 0;
    if (t < b) {
        int w;
        do { w = atomicAdd(&bsum[t], 0); } while (!(w & SCAN_FLAG));
        pv = w & ~SCAN_FLAG;
    }
    __syncthreads();
    s[t] = pv;
    __syncthreads();
    for (int off = 128; off > 0; off >>= 1) {
        if (t < off) s[t] += s[t + off];
        __syncthreads();
    }
    const int boffs = s[0];

    if (idx < N_NODES) {
        int rp = boffs + incl - v;
        rowptr[idx] = rp;
        cursor[idx] = rp;
        invdeg[idx] = 1.0f / fmaxf((float)v, 1.0f);
    }
    if (b == N_SCAN_BLOCKS - 1 && t == 255) rowptr[N_NODES] = boffs + incl;
}

// ================= CSR: fill (single atomic, absolute position) =================
__global__ void fill_kernel(const int* __restrict__ src, const int* __restrict__ dst,
                            int* __restrict__ cursor, int* __restrict__ eidx, int E) {
    int e = blockIdx.x * 256 + threadIdx.x;
    if (e < E) {
        int pos = atomicAdd(&cursor[dst[e]], 1);
        eidx[pos] = src[e];
    }
}

// ================= fp16 gather-aggregate: 4 nodes per wave, 16 lanes x 16 B =================
#define AGG8(vv, aa, ab) { aa.x += (float)vv[0]; aa.y += (float)vv[1]; \
                           aa.z += (float)vv[2]; aa.w += (float)vv[3]; \
                           ab.x += (float)vv[4]; ab.y += (float)vv[5]; \
                           ab.z += (float)vv[6]; ab.w += (float)vv[7]; }

__global__ __launch_bounds__(256) void aggregate_f16(
    const __half* __restrict__ feat16, const int* __restrict__ rowptr,
    const int* __restrict__ eidx, const float* __restrict__ invdeg,
    __half* __restrict__ mean16) {
    const int wave = threadIdx.x >> 6;
    const int lane = threadIdx.x & 63;
    const int nh   = lane >> 4;
    const int sub  = lane & 15;
    const int node = blockIdx.x * 16 + wave * 4 + nh;
    const bool act = (node < N_NODES);
    int beg = 0, end = 0;
    if (act) { beg = rowptr[node]; end = rowptr[node + 1]; }
    const size_t coff = (size_t)sub * 8;

    float4 a0 = {0.f,0.f,0.f,0.f}, b0 = {0.f,0.f,0.f,0.f};
    float4 a1 = {0.f,0.f,0.f,0.f}, b1 = {0.f,0.f,0.f,0.f};
    float4 a2 = {0.f,0.f,0.f,0.f}, b2 = {0.f,0.f,0.f,0.f};
    float4 a3 = {0.f,0.f,0.f,0.f}, b3 = {0.f,0.f,0.f,0.f};
    int i = beg;
    for (; i + 8 <= end; i += 8) {
        int s0 = eidx[i+0], s1 = eidx[i+1], s2 = eidx[i+2], s3 = eidx[i+3];
        int s4 = eidx[i+4], s5 = eidx[i+5], s6 = eidx[i+6], s7 = eidx[i+7];
        half8 v0 = *(const half8*)(feat16 + (size_t)s0 * 128 + coff);
        half8 v1 = *(const half8*)(feat16 + (size_t)s1 * 128 + coff);
        half8 v2 = *(const half8*)(feat16 + (size_t)s2 * 128 + coff);
        half8 v3 = *(const half8*)(feat16 + (size_t)s3 * 128 + coff);
        half8 v4 = *(const half8*)(feat16 + (size_t)s4 * 128 + coff);
        half8 v5 = *(const half8*)(feat16 + (size_t)s5 * 128 + coff);
        half8 v6 = *(const half8*)(feat16 + (size_t)s6 * 128 + coff);
        half8 v7 = *(const half8*)(feat16 + (size_t)s7 * 128 + coff);
        AGG8(v0, a0, b0); AGG8(v1, a1, b1); AGG8(v2, a2, b2); AGG8(v3, a3, b3);
        AGG8(v4, a0, b0); AGG8(v5, a1, b1); AGG8(v6, a2, b2); AGG8(v7, a3, b3);
    }
    if (i + 4 <= end) {
        int s0 = eidx[i+0], s1 = eidx[i+1], s2 = eidx[i+2], s3 = eidx[i+3];
        half8 v0 = *(const half8*)(feat16 + (size_t)s0 * 128 + coff);
        half8 v1 = *(const half8*)(feat16 + (size_t)s1 * 128 + coff);
        half8 v2 = *(const half8*)(feat16 + (size_t)s2 * 128 + coff);
        half8 v3 = *(const half8*)(feat16 + (size_t)s3 * 128 + coff);
        AGG8(v0, a0, b0); AGG8(v1, a1, b1); AGG8(v2, a2, b2); AGG8(v3, a3, b3);
        i += 4;
    }
    if (i + 2 <= end) {
        int s0 = eidx[i+0], s1 = eidx[i+1];
        half8 v0 = *(const half8*)(feat16 + (size_t)s0 * 128 + coff);
        half8 v1 = *(const half8*)(feat16 + (size_t)s1 * 128 + coff);
        AGG8(v0, a0, b0); AGG8(v1, a1, b1);
        i += 2;
    }
    if (i < end) {
        int s0 = eidx[i];
        half8 v0 = *(const half8*)(feat16 + (size_t)s0 * 128 + coff);
        AGG8(v0, a0, b0);
    }

    if (act) {
        const float sc = invdeg[node];
        half8 r;
        r[0] = (_Float16)(((a0.x + a1.x) + (a2.x + a3.x)) * sc);
        r[1] = (_Float16)(((a0.y + a1.y) + (a2.y + a3.y)) * sc);
        r[2] = (_Float16)(((a0.z + a1.z) + (a2.z + a3.z)) * sc);
        r[3] = (_Float16)(((a0.w + a1.w) + (a2.w + a3.w)) * sc);
        r[4] = (_Float16)(((b0.x + b1.x) + (b2.x + b3.x)) * sc);
        r[5] = (_Float16)(((b0.y + b1.y) + (b2.y + b3.y)) * sc);
        r[6] = (_Float16)(((b0.z + b1.z) + (b2.z + b3.z)) * sc);
        r[7] = (_Float16)(((b0.w + b1.w) + (b2.w + b3.w)) * sc);
        *(half8*)(mean16 + (size_t)node * 128 + coff) = r;
    }
}

// ================= fp16 MFMA SAGE GEMM (M=50000, N=128, K=256) =================
// A fragments prefetched to registers; B direct from global Wt (64 KB, L2-broadcast).
// Optional fused pooling epilogue (pooled != nullptr): LDS pre-reduce by local
// graph id (block's 64 consecutive rows span ~1-2 graphs), then ~256 global atomics.
#define GBM 64

__global__ __launch_bounds__(256) void sage_gemm_f16(
    const __half* __restrict__ mean16, const __half* __restrict__ feat16,
    const __half* __restrict__ Wt, const float* __restrict__ bias,
    const int* __restrict__ batch, __half* __restrict__ out16,
    float* __restrict__ pooled, int M) {
    __shared__ float pool_lds[8][128];

    const int tid = threadIdx.x;
    const int wave = tid >> 6;
    const int lane = tid & 63;
    const int l15 = lane & 15;
    const int quad = lane >> 4;
    const int row0 = blockIdx.x * GBM;
    const int gi_a = min(row0 + wave * 16 + l15, M - 1);

    if (pooled) {
        for (int i = tid; i < 8 * 128; i += 256) pool_lds[i >> 7][i & 127] = 0.f;
    }

    // prefetch all 8 A fragments (16 B each, coalesced across l15)
    half8 af[8];
#pragma unroll
    for (int kb = 0; kb < 8; ++kb) {
        const int k0 = kb * 32;
        const __half* ap = (k0 < 128)
            ? (mean16 + (size_t)gi_a * 128 + k0 + quad * 8)
            : (feat16 + (size_t)gi_a * 128 + (k0 - 128) + quad * 8);
        af[kb] = *(const half8*)ap;
    }

    f32x4 acc[8];
#pragma unroll
    for (int t = 0; t < 8; ++t) acc[t] = (f32x4){0.f, 0.f, 0.f, 0.f};

    if (pooled) __syncthreads();   // pool_lds zero visible before epilogue atomics

#pragma unroll
    for (int kb = 0; kb < 8; ++kb) {
#pragma unroll
        for (int t = 0; t < 8; ++t) {
            const half8 b = *(const half8*)(Wt + (size_t)(t * 16 + l15) * 256 + kb * 32 + quad * 8);
            acc[t] = __builtin_amdgcn_mfma_f32_16x16x32_f16(af[kb], b, acc[t], 0, 0, 0);
        }
    }

    if (pooled) {
        const int gmin = batch[row0];
#pragma unroll
        for (int r = 0; r < 4; ++r) {
            int gi = row0 + wave * 16 + quad * 4 + r;
            if (gi < M) {
                int gl = batch[gi] - gmin;
#pragma unroll
                for (int t = 0; t < 8; ++t) {
                    int col = t * 16 + l15;
                    float v = fmaxf(acc[t][r] + bias[col], 0.f);
                    if (gl < 8) atomicAdd(&pool_lds[gl][col], v);
                    else        atomicAdd(&pooled[(gmin + gl) * 128 + col], v);
                }
            }
        }
        __syncthreads();
        for (int i = tid; i < 8 * 128; i += 256) {
            int gl = i >> 7, c = i & 127;
            float v = pool_lds[gl][c];
            if (v != 0.f) atomicAdd(&pooled[(gmin + gl) * 128 + c], v);
        }
    } else {
#pragma unroll
        for (int r = 0; r < 4; ++r) {
            int gi = row0 + wave * 16 + quad * 4 + r;
            if (gi < M) {
#pragma unroll
                for (int t = 0; t < 8; ++t) {
                    int col = t * 16 + l15;
                    float v = fmaxf(acc[t][r] + bias[col], 0.f);
                    out16[(size_t)gi * 128 + col] = __float2half(v);
                }
            }
        }
    }
}

// ================= final linear =================
__global__ void final_kernel(const float* __restrict__ pooled,
                             const int* __restrict__ gstart,
                             const float* __restrict__ Wlin, const float* __restrict__ blin,
                             float* __restrict__ out) {
    int g = blockIdx.x;
    int j = threadIdx.x;               // 0..31
    float inv = 1.0f / fmaxf((float)(gstart[g + 1] - gstart[g]), 1.0f);
    float sum = blin[j];
    const float* w = Wlin + j * 128;
    const float* p = pooled + (size_t)g * 128;
    for (int c = 0; c < 128; ++c) sum += p[c] * inv * w[c];
    out[g * 32 + j] = sum;
}

extern "C" void kernel_launch(void* const* d_in, const int* in_sizes, int n_in,
                              void* d_out, int out_size, void* d_ws, size_t ws_size,
                              hipStream_t stream) {
    const float* x    = (const float*)d_in[0];
    const int*   src  = (const int*)d_in[1];
    const int*   dst  = ((const int*)d_in[1]) + N_EDGES;
    const int*   batch= (const int*)d_in[2];
    const float* W1l  = (const float*)d_in[3];
    const float* b1   = (const float*)d_in[4];
    const float* W1r  = (const float*)d_in[5];
    const float* W2l  = (const float*)d_in[6];
    const float* b2   = (const float*)d_in[7];
    const float* W2r  = (const float*)d_in[8];
    const float* Wlin = (const float*)d_in[9];
    const float* blin = (const float*)d_in[10];
    float* out = (float*)d_out;

    __half* xh     = (__half*)d_ws;                 // 6,400,000 h
    __half* mean16 = xh + 6400000;                  // 6,400,000 h
    __half* h1_16  = mean16 + 6400000;              // 6,400,000 h
    __half* Wt1    = h1_16 + 6400000;               // 32,768 h
    __half* Wt2    = Wt1 + 32768;                   // 32,768 h
    float* invdeg  = (float*)(Wt2 + 32768);         // 50,000 f
    int*   gstart  = (int*)(invdeg + N_NODES);      // 65 i
    // contiguous zero region: pooled, degi, bsum
    float* pooled  = (float*)(gstart + 65);         // 8,192 f
    int*   degi    = (int*)(pooled + N_GRAPHS * 128); // 50,000 i
    int*   bsum    = degi + N_NODES;                // 196 i
    int*   cursor  = bsum + N_SCAN_BLOCKS;          // 50,000 i (init'd by scan)
    int*   rowptr  = cursor + N_NODES;              // 50,001 i
    int*   eidx    = rowptr + N_NODES + 1;          // 600,000 i

    // 1) prep: zero {pooled,degi,bsum} + casts + graph boundaries
    prep_kernel<<<16 + (N_NODES * 128 / 4 + 255) / 256, 256, 0, stream>>>(
        x, batch, W1l, W1r, W2l, W2r, xh, Wt1, Wt2, (int*)pooled, gstart);

    // 2-4) CSR: degrees -> fused lookback scan (inits cursor) -> fill
    deg_kernel<<<(N_EDGES + 255) / 256, 256, 0, stream>>>(dst, degi, N_EDGES);
    scan_fused<<<N_SCAN_BLOCKS, 256, 0, stream>>>(degi, bsum, rowptr, cursor, invdeg);
    fill_kernel<<<(N_EDGES + 255) / 256, 256, 0, stream>>>(src, dst, cursor, eidx, N_EDGES);

    const int gemm_grid = (N_NODES + GBM - 1) / GBM;   // 782
    const int agg_grid = (N_NODES + 15) / 16;          // 3125

    // 5-6) layer 1: gather -> GEMM (stores h1 fp16)
    aggregate_f16<<<agg_grid, 256, 0, stream>>>(xh, rowptr, eidx, invdeg, mean16);
    sage_gemm_f16<<<gemm_grid, 256, 0, stream>>>(mean16, xh, Wt1, b1, batch,
                                                 h1_16, (float*)nullptr, N_NODES);

    // 7-8) layer 2: gather -> GEMM with fused pooling (h2 never materialized)
    aggregate_f16<<<agg_grid, 256, 0, stream>>>(h1_16, rowptr, eidx, invdeg, mean16);
    sage_gemm_f16<<<gemm_grid, 256, 0, stream>>>(mean16, h1_16, Wt2, b2, batch,
                                                 (__half*)nullptr, pooled, N_NODES);

    // 9) final linear
    final_kernel<<<N_GRAPHS, 32, 0, stream>>>(pooled, gstart, Wlin, blin, out);
}

// Round 15
// 282.362 us; speedup vs baseline: 1.1405x; 1.1405x over previous
//
#include <hip/hip_runtime.h>
#include <hip/hip_fp16.h>

#define N_NODES 50000
#define N_EDGES 600000
#define N_GRAPHS 64
#define HID 128
#define OUT_C 32

#define N_SCAN_BLOCKS ((N_NODES + 255) / 256)   // 196
#define SCAN_FLAG 0x40000000

typedef __attribute__((ext_vector_type(8))) _Float16 half8;
typedef __attribute__((ext_vector_type(4))) float f32x4;

// ================= prep: zero {pooled,degi,bsum} + fp16 casts + graph boundaries ==========
#define ZERO_INTS (N_GRAPHS * 128 + N_NODES + N_SCAN_BLOCKS)   // pooled + degi + bsum

__global__ __launch_bounds__(256) void prep_kernel(
    const float* __restrict__ x, const int* __restrict__ batch,
    const float* __restrict__ W1l, const float* __restrict__ W1r,
    const float* __restrict__ W2l, const float* __restrict__ W2r,
    __half* __restrict__ xh, __half* __restrict__ Wt1, __half* __restrict__ Wt2,
    int* __restrict__ zero_base, int* __restrict__ gstart) {
    const int b = blockIdx.x;
    const int t = threadIdx.x;
    const int gtid = b * 256 + t;
    const int gsz = gridDim.x * 256;
    for (int i = gtid; i < ZERO_INTS; i += gsz) zero_base[i] = 0;

    // graph boundaries from sorted batch
    for (int i = gtid; i <= N_NODES; i += gsz) {
        if (i == 0) {
            int b1 = batch[0];
            for (int g = 0; g <= b1; ++g) gstart[g] = 0;
        } else if (i == N_NODES) {
            int b0 = batch[N_NODES - 1];
            for (int g = b0 + 1; g <= N_GRAPHS; ++g) gstart[g] = N_NODES;
        } else {
            int b0 = batch[i - 1], b1 = batch[i];
            for (int g = b0 + 1; g <= b1; ++g) gstart[g] = i;
        }
    }

    if (b < 16) {
        for (int i = gtid; i < 65536; i += 4096) {
            int which = i >> 15;
            int j = i & 32767;
            int n = j >> 8, k = j & 255;
            const float* Wl = which ? W2l : W1l;
            const float* Wr = which ? W2r : W1r;
            float a = (k < 128) ? Wl[n * 128 + k] : Wr[n * 128 + (k - 128)];
            (which ? Wt2 : Wt1)[j] = __float2half(a);
        }
    } else {
        int i = ((b - 16) * 256 + t) * 4;
        if (i < N_NODES * 128) {
            float4 v = *(const float4*)(x + i);
            __half2 a = __floats2half2_rn(v.x, v.y);
            __half2 c = __floats2half2_rn(v.z, v.w);
            uint2 st;
            st.x = *(const unsigned int*)&a;
            st.y = *(const unsigned int*)&c;
            *(uint2*)(xh + i) = st;
        }
    }
}

// ================= CSR: degrees =================
__global__ void deg_kernel(const int* __restrict__ dst, int* __restrict__ deg, int E) {
    int e = blockIdx.x * 256 + threadIdx.x;
    if (e < E) atomicAdd(&deg[dst[e]], 1);
}

// ================= CSR: single-dispatch scan (decoupled lookback); inits cursor ==========
__global__ __launch_bounds__(256) void scan_fused(
    const int* __restrict__ deg, int* __restrict__ bsum,
    int* __restrict__ rowptr, int* __restrict__ cursor, float* __restrict__ invdeg) {
    __shared__ int s[256];
    const int b = blockIdx.x;
    const int t = threadIdx.x;
    const int idx = b * 256 + t;
    const int v = (idx < N_NODES) ? deg[idx] : 0;
    s[t] = v;
    __syncthreads();
    for (int off = 1; off < 256; off <<= 1) {
        int u = (t >= off) ? s[t - off] : 0;
        __syncthreads();
        s[t] += u;
        __syncthreads();
    }
    const int incl = s[t];
    if (t == 255) atomicExch(&bsum[b], incl | SCAN_FLAG);

    int pv = 0;
    if (t < b) {
        int w;
        do { w = atomicAdd(&bsum[t], 0); } while (!(w & SCAN_FLAG));
        pv = w & ~SCAN_FLAG;
    }
    __syncthreads();
    s[t] = pv;
    __syncthreads();
    for (int off = 128; off > 0; off >>= 1) {
        if (t < off) s[t] += s[t + off];
        __syncthreads();
    }
    const int boffs = s[0];

    if (idx < N_NODES) {
        int rp = boffs + incl - v;
        rowptr[idx] = rp;
        cursor[idx] = rp;
        invdeg[idx] = 1.0f / fmaxf((float)v, 1.0f);
    }
    if (b == N_SCAN_BLOCKS - 1 && t == 255) rowptr[N_NODES] = boffs + incl;
}

// ================= CSR: fill (single atomic, absolute position) =================
__global__ void fill_kernel(const int* __restrict__ src, const int* __restrict__ dst,
                            int* __restrict__ cursor, int* __restrict__ eidx, int E) {
    int e = blockIdx.x * 256 + threadIdx.x;
    if (e < E) {
        int pos = atomicAdd(&cursor[dst[e]], 1);
        eidx[pos] = src[e];
    }
}

// ================= fp16 gather-aggregate: 4 nodes per wave, 16 lanes x 16 B =================
#define AGG8(vv, aa, ab) { aa.x += (float)vv[0]; aa.y += (float)vv[1]; \
                           aa.z += (float)vv[2]; aa.w += (float)vv[3]; \
                           ab.x += (float)vv[4]; ab.y += (float)vv[5]; \
                           ab.z += (float)vv[6]; ab.w += (float)vv[7]; }

__global__ __launch_bounds__(256) void aggregate_f16(
    const __half* __restrict__ feat16, const int* __restrict__ rowptr,
    const int* __restrict__ eidx, const float* __restrict__ invdeg,
    __half* __restrict__ mean16) {
    const int wave = threadIdx.x >> 6;
    const int lane = threadIdx.x & 63;
    const int nh   = lane >> 4;
    const int sub  = lane & 15;
    const int node = blockIdx.x * 16 + wave * 4 + nh;
    const bool act = (node < N_NODES);
    int beg = 0, end = 0;
    if (act) { beg = rowptr[node]; end = rowptr[node + 1]; }
    const size_t coff = (size_t)sub * 8;

    float4 a0 = {0.f,0.f,0.f,0.f}, b0 = {0.f,0.f,0.f,0.f};
    float4 a1 = {0.f,0.f,0.f,0.f}, b1 = {0.f,0.f,0.f,0.f};
    float4 a2 = {0.f,0.f,0.f,0.f}, b2 = {0.f,0.f,0.f,0.f};
    float4 a3 = {0.f,0.f,0.f,0.f}, b3 = {0.f,0.f,0.f,0.f};
    int i = beg;
    for (; i + 8 <= end; i += 8) {
        int s0 = eidx[i+0], s1 = eidx[i+1], s2 = eidx[i+2], s3 = eidx[i+3];
        int s4 = eidx[i+4], s5 = eidx[i+5], s6 = eidx[i+6], s7 = eidx[i+7];
        half8 v0 = *(const half8*)(feat16 + (size_t)s0 * 128 + coff);
        half8 v1 = *(const half8*)(feat16 + (size_t)s1 * 128 + coff);
        half8 v2 = *(const half8*)(feat16 + (size_t)s2 * 128 + coff);
        half8 v3 = *(const half8*)(feat16 + (size_t)s3 * 128 + coff);
        half8 v4 = *(const half8*)(feat16 + (size_t)s4 * 128 + coff);
        half8 v5 = *(const half8*)(feat16 + (size_t)s5 * 128 + coff);
        half8 v6 = *(const half8*)(feat16 + (size_t)s6 * 128 + coff);
        half8 v7 = *(const half8*)(feat16 + (size_t)s7 * 128 + coff);
        AGG8(v0, a0, b0); AGG8(v1, a1, b1); AGG8(v2, a2, b2); AGG8(v3, a3, b3);
        AGG8(v4, a0, b0); AGG8(v5, a1, b1); AGG8(v6, a2, b2); AGG8(v7, a3, b3);
    }
    if (i + 4 <= end) {
        int s0 = eidx[i+0], s1 = eidx[i+1], s2 = eidx[i+2], s3 = eidx[i+3];
        half8 v0 = *(const half8*)(feat16 + (size_t)s0 * 128 + coff);
        half8 v1 = *(const half8*)(feat16 + (size_t)s1 * 128 + coff);
        half8 v2 = *(const half8*)(feat16 + (size_t)s2 * 128 + coff);
        half8 v3 = *(const half8*)(feat16 + (size_t)s3 * 128 + coff);
        AGG8(v0, a0, b0); AGG8(v1, a1, b1); AGG8(v2, a2, b2); AGG8(v3, a3, b3);
        i += 4;
    }
    if (i + 2 <= end) {
        int s0 = eidx[i+0], s1 = eidx[i+1];
        half8 v0 = *(const half8*)(feat16 + (size_t)s0 * 128 + coff);
        half8 v1 = *(const half8*)(feat16 + (size_t)s1 * 128 + coff);
        AGG8(v0, a0, b0); AGG8(v1, a1, b1);
        i += 2;
    }
    if (i < end) {
        int s0 = eidx[i];
        half8 v0 = *(const half8*)(feat16 + (size_t)s0 * 128 + coff);
        AGG8(v0, a0, b0);
    }

    if (act) {
        const float sc = invdeg[node];
        half8 r;
        r[0] = (_Float16)(((a0.x + a1.x) + (a2.x + a3.x)) * sc);
        r[1] = (_Float16)(((a0.y + a1.y) + (a2.y + a3.y)) * sc);
        r[2] = (_Float16)(((a0.z + a1.z) + (a2.z + a3.z)) * sc);
        r[3] = (_Float16)(((a0.w + a1.w) + (a2.w + a3.w)) * sc);
        r[4] = (_Float16)(((b0.x + b1.x) + (b2.x + b3.x)) * sc);
        r[5] = (_Float16)(((b0.y + b1.y) + (b2.y + b3.y)) * sc);
        r[6] = (_Float16)(((b0.z + b1.z) + (b2.z + b3.z)) * sc);
        r[7] = (_Float16)(((b0.w + b1.w) + (b2.w + b3.w)) * sc);
        *(half8*)(mean16 + (size_t)node * 128 + coff) = r;
    }
}

// ================= fp16 MFMA SAGE GEMM (M=50000, N=128, K=256) =================
// B staged ONCE into LDS (R12-proven: MFMA feeds must be LDS/registers, not L2);
// A fragments prefetched to registers. Optional fused pooling epilogue
// (pooled != nullptr): LDS pre-reduce by local graph id, then ~256 global atomics.
#define GBM 64
#define BPAD 8

__global__ __launch_bounds__(256) void sage_gemm_f16(
    const __half* __restrict__ mean16, const __half* __restrict__ feat16,
    const __half* __restrict__ Wt, const float* __restrict__ bias,
    const int* __restrict__ batch, __half* __restrict__ out16,
    float* __restrict__ pooled, int M) {
    __shared__ __align__(16) __half Bs[128][256 + BPAD];
    __shared__ float pool_lds[8][128];

    const int tid = threadIdx.x;
    const int wave = tid >> 6;
    const int lane = tid & 63;
    const int l15 = lane & 15;
    const int quad = lane >> 4;
    const int row0 = blockIdx.x * GBM;
    const int gi_a = min(row0 + wave * 16 + l15, M - 1);   // clamp OOB (stores guarded)

    // stage all of B: 128 rows x 32 half8
    for (int id = tid; id < 128 * 32; id += 256) {
        int n = id >> 5;
        int kc = (id & 31) * 8;
        *(half8*)&Bs[n][kc] = *(const half8*)(Wt + (size_t)n * 256 + kc);
    }
    if (pooled) {
        for (int i = tid; i < 8 * 128; i += 256) pool_lds[i >> 7][i & 127] = 0.f;
    }

    // prefetch all 8 A fragments (16 B each, coalesced across l15)
    half8 af[8];
#pragma unroll
    for (int kb = 0; kb < 8; ++kb) {
        const int k0 = kb * 32;
        const __half* ap = (k0 < 128)
            ? (mean16 + (size_t)gi_a * 128 + k0 + quad * 8)
            : (feat16 + (size_t)gi_a * 128 + (k0 - 128) + quad * 8);
        af[kb] = *(const half8*)ap;
    }

    f32x4 acc[8];
#pragma unroll
    for (int t = 0; t < 8; ++t) acc[t] = (f32x4){0.f, 0.f, 0.f, 0.f};

    __syncthreads();

#pragma unroll
    for (int kb = 0; kb < 8; ++kb) {
#pragma unroll
        for (int t = 0; t < 8; ++t) {
            const half8 b = *(const half8*)&Bs[t * 16 + l15][kb * 32 + quad * 8];
            acc[t] = __builtin_amdgcn_mfma_f32_16x16x32_f16(af[kb], b, acc[t], 0, 0, 0);
        }
    }

    if (pooled) {
        const int gmin = batch[row0];
#pragma unroll
        for (int r = 0; r < 4; ++r) {
            int gi = row0 + wave * 16 + quad * 4 + r;
            if (gi < M) {
                int gl = batch[gi] - gmin;
#pragma unroll
                for (int t = 0; t < 8; ++t) {
                    int col = t * 16 + l15;
                    float v = fmaxf(acc[t][r] + bias[col], 0.f);
                    if (gl < 8) atomicAdd(&pool_lds[gl][col], v);
                    else        atomicAdd(&pooled[(gmin + gl) * 128 + col], v);
                }
            }
        }
        __syncthreads();
        for (int i = tid; i < 8 * 128; i += 256) {
            int gl = i >> 7, c = i & 127;
            float v = pool_lds[gl][c];
            if (v != 0.f) atomicAdd(&pooled[(gmin + gl) * 128 + c], v);
        }
    } else {
#pragma unroll
        for (int r = 0; r < 4; ++r) {
            int gi = row0 + wave * 16 + quad * 4 + r;
            if (gi < M) {
#pragma unroll
                for (int t = 0; t < 8; ++t) {
                    int col = t * 16 + l15;
                    float v = fmaxf(acc[t][r] + bias[col], 0.f);
                    out16[(size_t)gi * 128 + col] = __float2half(v);
                }
            }
        }
    }
}

// ================= final linear =================
__global__ void final_kernel(const float* __restrict__ pooled,
                             const int* __restrict__ gstart,
                             const float* __restrict__ Wlin, const float* __restrict__ blin,
                             float* __restrict__ out) {
    int g = blockIdx.x;
    int j = threadIdx.x;               // 0..31
    float inv = 1.0f / fmaxf((float)(gstart[g + 1] - gstart[g]), 1.0f);
    float sum = blin[j];
    const float* w = Wlin + j * 128;
    const float* p = pooled + (size_t)g * 128;
    for (int c = 0; c < 128; ++c) sum += p[c] * inv * w[c];
    out[g * 32 + j] = sum;
}

extern "C" void kernel_launch(void* const* d_in, const int* in_sizes, int n_in,
                              void* d_out, int out_size, void* d_ws, size_t ws_size,
                              hipStream_t stream) {
    const float* x    = (const float*)d_in[0];
    const int*   src  = (const int*)d_in[1];
    const int*   dst  = ((const int*)d_in[1]) + N_EDGES;
    const int*   batch= (const int*)d_in[2];
    const float* W1l  = (const float*)d_in[3];
    const float* b1   = (const float*)d_in[4];
    const float* W1r  = (const float*)d_in[5];
    const float* W2l  = (const float*)d_in[6];
    const float* b2   = (const float*)d_in[7];
    const float* W2r  = (const float*)d_in[8];
    const float* Wlin = (const float*)d_in[9];
    const float* blin = (const float*)d_in[10];
    float* out = (float*)d_out;

    __half* xh     = (__half*)d_ws;                 // 6,400,000 h
    __half* mean16 = xh + 6400000;                  // 6,400,000 h
    __half* h1_16  = mean16 + 6400000;              // 6,400,000 h
    __half* Wt1    = h1_16 + 6400000;               // 32,768 h
    __half* Wt2    = Wt1 + 32768;                   // 32,768 h
    float* invdeg  = (float*)(Wt2 + 32768);         // 50,000 f
    int*   gstart  = (int*)(invdeg + N_NODES);      // 65 i
    // contiguous zero region: pooled, degi, bsum
    float* pooled  = (float*)(gstart + 65);         // 8,192 f
    int*   degi    = (int*)(pooled + N_GRAPHS * 128); // 50,000 i
    int*   bsum    = degi + N_NODES;                // 196 i
    int*   cursor  = bsum + N_SCAN_BLOCKS;          // 50,000 i (init'd by scan)
    int*   rowptr  = cursor + N_NODES;              // 50,001 i
    int*   eidx    = rowptr + N_NODES + 1;          // 600,000 i

    // 1) prep: zero {pooled,degi,bsum} + casts + graph boundaries
    prep_kernel<<<16 + (N_NODES * 128 / 4 + 255) / 256, 256, 0, stream>>>(
        x, batch, W1l, W1r, W2l, W2r, xh, Wt1, Wt2, (int*)pooled, gstart);

    // 2-4) CSR: degrees -> fused lookback scan (inits cursor) -> fill
    deg_kernel<<<(N_EDGES + 255) / 256, 256, 0, stream>>>(dst, degi, N_EDGES);
    scan_fused<<<N_SCAN_BLOCKS, 256, 0, stream>>>(degi, bsum, rowptr, cursor, invdeg);
    fill_kernel<<<(N_EDGES + 255) / 256, 256, 0, stream>>>(src, dst, cursor, eidx, N_EDGES);

    const int gemm_grid = (N_NODES + GBM - 1) / GBM;   // 782
    const int agg_grid = (N_NODES + 15) / 16;          // 3125

    // 5-6) layer 1: gather -> GEMM (stores h1 fp16)
    aggregate_f16<<<agg_grid, 256, 0, stream>>>(xh, rowptr, eidx, invdeg, mean16);
    sage_gemm_f16<<<gemm_grid, 256, 0, stream>>>(mean16, xh, Wt1, b1, batch,
                                                 h1_16, (float*)nullptr, N_NODES);

    // 7-8) layer 2: gather -> GEMM with fused pooling (h2 never materialized)
    aggregate_f16<<<agg_grid, 256, 0, stream>>>(h1_16, rowptr, eidx, invdeg, mean16);
    sage_gemm_f16<<<gemm_grid, 256, 0, stream>>>(mean16, h1_16, Wt2, b2, batch,
                                                 (__half*)nullptr, pooled, N_NODES);

    // 9) final linear
    final_kernel<<<N_GRAPHS, 32, 0, stream>>>(pooled, gstart, Wlin, blin, out);
}

// Round 16
// 281.049 us; speedup vs baseline: 1.1459x; 1.0047x over previous
//
#include <hip/hip_runtime.h>
#include <hip/hip_fp16.h>

#define N_NODES 50000
#define N_EDGES 600000
#define N_GRAPHS 64
#define HID 128
#define OUT_C 32

#define N_SCAN_BLOCKS ((N_NODES + 255) / 256)   // 196
#define SCAN_FLAG 0x40000000

typedef __attribute__((ext_vector_type(8))) _Float16 half8;
typedef __attribute__((ext_vector_type(4))) float f32x4;

// ================= prep: zero {pooled,degi,bsum} + fp16 casts + graph boundaries ==========
#define ZERO_INTS (N_GRAPHS * 128 + N_NODES + N_SCAN_BLOCKS)   // pooled + degi + bsum

__global__ __launch_bounds__(256) void prep_kernel(
    const float* __restrict__ x, const int* __restrict__ batch,
    const float* __restrict__ W1l, const float* __restrict__ W1r,
    const float* __restrict__ W2l, const float* __restrict__ W2r,
    __half* __restrict__ xh, __half* __restrict__ Wt1, __half* __restrict__ Wt2,
    int* __restrict__ zero_base, int* __restrict__ gstart) {
    const int b = blockIdx.x;
    const int t = threadIdx.x;
    const int gtid = b * 256 + t;
    const int gsz = gridDim.x * 256;
    for (int i = gtid; i < ZERO_INTS; i += gsz) zero_base[i] = 0;

    // graph boundaries from sorted batch
    for (int i = gtid; i <= N_NODES; i += gsz) {
        if (i == 0) {
            int b1 = batch[0];
            for (int g = 0; g <= b1; ++g) gstart[g] = 0;
        } else if (i == N_NODES) {
            int b0 = batch[N_NODES - 1];
            for (int g = b0 + 1; g <= N_GRAPHS; ++g) gstart[g] = N_NODES;
        } else {
            int b0 = batch[i - 1], b1 = batch[i];
            for (int g = b0 + 1; g <= b1; ++g) gstart[g] = i;
        }
    }

    if (b < 16) {
        for (int i = gtid; i < 65536; i += 4096) {
            int which = i >> 15;
            int j = i & 32767;
            int n = j >> 8, k = j & 255;
            const float* Wl = which ? W2l : W1l;
            const float* Wr = which ? W2r : W1r;
            float a = (k < 128) ? Wl[n * 128 + k] : Wr[n * 128 + (k - 128)];
            (which ? Wt2 : Wt1)[j] = __float2half(a);
        }
    } else {
        int i = ((b - 16) * 256 + t) * 4;
        if (i < N_NODES * 128) {
            float4 v = *(const float4*)(x + i);
            __half2 a = __floats2half2_rn(v.x, v.y);
            __half2 c = __floats2half2_rn(v.z, v.w);
            uint2 st;
            st.x = *(const unsigned int*)&a;
            st.y = *(const unsigned int*)&c;
            *(uint2*)(xh + i) = st;
        }
    }
}

// ================= CSR: degrees =================
__global__ void deg_kernel(const int* __restrict__ dst, int* __restrict__ deg, int E) {
    int e = blockIdx.x * 256 + threadIdx.x;
    if (e < E) atomicAdd(&deg[dst[e]], 1);
}

// ================= CSR: single-dispatch scan (decoupled lookback); inits cursor ==========
__global__ __launch_bounds__(256) void scan_fused(
    const int* __restrict__ deg, int* __restrict__ bsum,
    int* __restrict__ rowptr, int* __restrict__ cursor, float* __restrict__ invdeg) {
    __shared__ int s[256];
    const int b = blockIdx.x;
    const int t = threadIdx.x;
    const int idx = b * 256 + t;
    const int v = (idx < N_NODES) ? deg[idx] : 0;
    s[t] = v;
    __syncthreads();
    for (int off = 1; off < 256; off <<= 1) {
        int u = (t >= off) ? s[t - off] : 0;
        __syncthreads();
        s[t] += u;
        __syncthreads();
    }
    const int incl = s[t];
    if (t == 255) atomicExch(&bsum[b], incl | SCAN_FLAG);

    int pv = 0;
    if (t < b) {
        int w;
        do { w = atomicAdd(&bsum[t], 0); } while (!(w & SCAN_FLAG));
        pv = w & ~SCAN_FLAG;
    }
    __syncthreads();
    s[t] = pv;
    __syncthreads();
    for (int off = 128; off > 0; off >>= 1) {
        if (t < off) s[t] += s[t + off];
        __syncthreads();
    }
    const int boffs = s[0];

    if (idx < N_NODES) {
        int rp = boffs + incl - v;
        rowptr[idx] = rp;
        cursor[idx] = rp;
        invdeg[idx] = 1.0f / fmaxf((float)v, 1.0f);
    }
    if (b == N_SCAN_BLOCKS - 1 && t == 255) rowptr[N_NODES] = boffs + incl;
}

// ================= CSR: fill (single atomic, absolute position) =================
__global__ void fill_kernel(const int* __restrict__ src, const int* __restrict__ dst,
                            int* __restrict__ cursor, int* __restrict__ eidx, int E) {
    int e = blockIdx.x * 256 + threadIdx.x;
    if (e < E) {
        int pos = atomicAdd(&cursor[dst[e]], 1);
        eidx[pos] = src[e];
    }
}

// ================= fp16 gather-aggregate: 4 nodes per wave, 16 lanes x 16 B =================
#define AGG8(vv, aa, ab) { aa.x += (float)vv[0]; aa.y += (float)vv[1]; \
                           aa.z += (float)vv[2]; aa.w += (float)vv[3]; \
                           ab.x += (float)vv[4]; ab.y += (float)vv[5]; \
                           ab.z += (float)vv[6]; ab.w += (float)vv[7]; }

__global__ __launch_bounds__(256) void aggregate_f16(
    const __half* __restrict__ feat16, const int* __restrict__ rowptr,
    const int* __restrict__ eidx, const float* __restrict__ invdeg,
    __half* __restrict__ mean16) {
    const int wave = threadIdx.x >> 6;
    const int lane = threadIdx.x & 63;
    const int nh   = lane >> 4;
    const int sub  = lane & 15;
    const int node = blockIdx.x * 16 + wave * 4 + nh;
    const bool act = (node < N_NODES);
    int beg = 0, end = 0;
    if (act) { beg = rowptr[node]; end = rowptr[node + 1]; }
    const size_t coff = (size_t)sub * 8;

    float4 a0 = {0.f,0.f,0.f,0.f}, b0 = {0.f,0.f,0.f,0.f};
    float4 a1 = {0.f,0.f,0.f,0.f}, b1 = {0.f,0.f,0.f,0.f};
    float4 a2 = {0.f,0.f,0.f,0.f}, b2 = {0.f,0.f,0.f,0.f};
    float4 a3 = {0.f,0.f,0.f,0.f}, b3 = {0.f,0.f,0.f,0.f};
    int i = beg;
    for (; i + 8 <= end; i += 8) {
        int s0 = eidx[i+0], s1 = eidx[i+1], s2 = eidx[i+2], s3 = eidx[i+3];
        int s4 = eidx[i+4], s5 = eidx[i+5], s6 = eidx[i+6], s7 = eidx[i+7];
        half8 v0 = *(const half8*)(feat16 + (size_t)s0 * 128 + coff);
        half8 v1 = *(const half8*)(feat16 + (size_t)s1 * 128 + coff);
        half8 v2 = *(const half8*)(feat16 + (size_t)s2 * 128 + coff);
        half8 v3 = *(const half8*)(feat16 + (size_t)s3 * 128 + coff);
        half8 v4 = *(const half8*)(feat16 + (size_t)s4 * 128 + coff);
        half8 v5 = *(const half8*)(feat16 + (size_t)s5 * 128 + coff);
        half8 v6 = *(const half8*)(feat16 + (size_t)s6 * 128 + coff);
        half8 v7 = *(const half8*)(feat16 + (size_t)s7 * 128 + coff);
        AGG8(v0, a0, b0); AGG8(v1, a1, b1); AGG8(v2, a2, b2); AGG8(v3, a3, b3);
        AGG8(v4, a0, b0); AGG8(v5, a1, b1); AGG8(v6, a2, b2); AGG8(v7, a3, b3);
    }
    if (i + 4 <= end) {
        int s0 = eidx[i+0], s1 = eidx[i+1], s2 = eidx[i+2], s3 = eidx[i+3];
        half8 v0 = *(const half8*)(feat16 + (size_t)s0 * 128 + coff);
        half8 v1 = *(const half8*)(feat16 + (size_t)s1 * 128 + coff);
        half8 v2 = *(const half8*)(feat16 + (size_t)s2 * 128 + coff);
        half8 v3 = *(const half8*)(feat16 + (size_t)s3 * 128 + coff);
        AGG8(v0, a0, b0); AGG8(v1, a1, b1); AGG8(v2, a2, b2); AGG8(v3, a3, b3);
        i += 4;
    }
    if (i + 2 <= end) {
        int s0 = eidx[i+0], s1 = eidx[i+1];
        half8 v0 = *(const half8*)(feat16 + (size_t)s0 * 128 + coff);
        half8 v1 = *(const half8*)(feat16 + (size_t)s1 * 128 + coff);
        AGG8(v0, a0, b0); AGG8(v1, a1, b1);
        i += 2;
    }
    if (i < end) {
        int s0 = eidx[i];
        half8 v0 = *(const half8*)(feat16 + (size_t)s0 * 128 + coff);
        AGG8(v0, a0, b0);
    }

    if (act) {
        const float sc = invdeg[node];
        half8 r;
        r[0] = (_Float16)(((a0.x + a1.x) + (a2.x + a3.x)) * sc);
        r[1] = (_Float16)(((a0.y + a1.y) + (a2.y + a3.y)) * sc);
        r[2] = (_Float16)(((a0.z + a1.z) + (a2.z + a3.z)) * sc);
        r[3] = (_Float16)(((a0.w + a1.w) + (a2.w + a3.w)) * sc);
        r[4] = (_Float16)(((b0.x + b1.x) + (b2.x + b3.x)) * sc);
        r[5] = (_Float16)(((b0.y + b1.y) + (b2.y + b3.y)) * sc);
        r[6] = (_Float16)(((b0.z + b1.z) + (b2.z + b3.z)) * sc);
        r[7] = (_Float16)(((b0.w + b1.w) + (b2.w + b3.w)) * sc);
        *(half8*)(mean16 + (size_t)node * 128 + coff) = r;
    }
}

// ================= fp16 MFMA SAGE GEMM, M-loop (M=50000, N=128, K=256) =================
// B staged ONCE per block; block processes MTILES consecutive 64-row tiles with
// A software-pipelined in registers (no barrier between tiles: B is read-only).
// Optional fused pooling epilogue accumulates into pool_lds across tiles.
#define GBM 64
#define MTILES 2
#define BPAD 8

__global__ __launch_bounds__(256) void sage_gemm_f16(
    const __half* __restrict__ mean16, const __half* __restrict__ feat16,
    const __half* __restrict__ Wt, const float* __restrict__ bias,
    const int* __restrict__ batch, __half* __restrict__ out16,
    float* __restrict__ pooled, int M) {
    __shared__ __align__(16) __half Bs[128][256 + BPAD];
    __shared__ float pool_lds[8][128];

    const int tid = threadIdx.x;
    const int wave = tid >> 6;
    const int lane = tid & 63;
    const int l15 = lane & 15;
    const int quad = lane >> 4;
    const int row_base = blockIdx.x * (GBM * MTILES);

    // stage all of B: 128 rows x 32 half8
    for (int id = tid; id < 128 * 32; id += 256) {
        int n = id >> 5;
        int kc = (id & 31) * 8;
        *(half8*)&Bs[n][kc] = *(const half8*)(Wt + (size_t)n * 256 + kc);
    }
    if (pooled) {
        for (int i = tid; i < 8 * 128; i += 256) pool_lds[i >> 7][i & 127] = 0.f;
    }

    // prefetch tile 0's A fragments
    half8 af[8];
    {
        const int gi0 = min(row_base + wave * 16 + l15, M - 1);
#pragma unroll
        for (int kb = 0; kb < 8; ++kb) {
            const int k0 = kb * 32;
            const __half* ap = (k0 < 128)
                ? (mean16 + (size_t)gi0 * 128 + k0 + quad * 8)
                : (feat16 + (size_t)gi0 * 128 + (k0 - 128) + quad * 8);
            af[kb] = *(const half8*)ap;
        }
    }

    __syncthreads();

    const int gmin = pooled ? batch[min(row_base, M - 1)] : 0;

    for (int t2 = 0; t2 < MTILES; ++t2) {
        const int row0 = row_base + t2 * GBM;

        // prefetch next tile's A while this tile's MFMAs run
        half8 afn[8];
        if (t2 + 1 < MTILES) {
            const int gin = min(row0 + GBM + wave * 16 + l15, M - 1);
#pragma unroll
            for (int kb = 0; kb < 8; ++kb) {
                const int k0 = kb * 32;
                const __half* ap = (k0 < 128)
                    ? (mean16 + (size_t)gin * 128 + k0 + quad * 8)
                    : (feat16 + (size_t)gin * 128 + (k0 - 128) + quad * 8);
                afn[kb] = *(const half8*)ap;
            }
        }

        f32x4 acc[8];
#pragma unroll
        for (int t = 0; t < 8; ++t) acc[t] = (f32x4){0.f, 0.f, 0.f, 0.f};

#pragma unroll
        for (int kb = 0; kb < 8; ++kb) {
#pragma unroll
            for (int t = 0; t < 8; ++t) {
                const half8 b = *(const half8*)&Bs[t * 16 + l15][kb * 32 + quad * 8];
                acc[t] = __builtin_amdgcn_mfma_f32_16x16x32_f16(af[kb], b, acc[t], 0, 0, 0);
            }
        }

        if (pooled) {
#pragma unroll
            for (int r = 0; r < 4; ++r) {
                int gi = row0 + wave * 16 + quad * 4 + r;
                if (gi < M) {
                    int gl = batch[gi] - gmin;
#pragma unroll
                    for (int t = 0; t < 8; ++t) {
                        int col = t * 16 + l15;
                        float v = fmaxf(acc[t][r] + bias[col], 0.f);
                        if (gl < 8) atomicAdd(&pool_lds[gl][col], v);
                        else        atomicAdd(&pooled[(gmin + gl) * 128 + col], v);
                    }
                }
            }
        } else {
#pragma unroll
            for (int r = 0; r < 4; ++r) {
                int gi = row0 + wave * 16 + quad * 4 + r;
                if (gi < M) {
#pragma unroll
                    for (int t = 0; t < 8; ++t) {
                        int col = t * 16 + l15;
                        float v = fmaxf(acc[t][r] + bias[col], 0.f);
                        out16[(size_t)gi * 128 + col] = __float2half(v);
                    }
                }
            }
        }

#pragma unroll
        for (int kb = 0; kb < 8; ++kb) af[kb] = afn[kb];
    }

    if (pooled) {
        __syncthreads();
        for (int i = tid; i < 8 * 128; i += 256) {
            int gl = i >> 7, c = i & 127;
            float v = pool_lds[gl][c];
            if (v != 0.f) atomicAdd(&pooled[(gmin + gl) * 128 + c], v);
        }
    }
}

// ================= final linear =================
__global__ void final_kernel(const float* __restrict__ pooled,
                             const int* __restrict__ gstart,
                             const float* __restrict__ Wlin, const float* __restrict__ blin,
                             float* __restrict__ out) {
    int g = blockIdx.x;
    int j = threadIdx.x;               // 0..31
    float inv = 1.0f / fmaxf((float)(gstart[g + 1] - gstart[g]), 1.0f);
    float sum = blin[j];
    const float* w = Wlin + j * 128;
    const float* p = pooled + (size_t)g * 128;
    for (int c = 0; c < 128; ++c) sum += p[c] * inv * w[c];
    out[g * 32 + j] = sum;
}

extern "C" void kernel_launch(void* const* d_in, const int* in_sizes, int n_in,
                              void* d_out, int out_size, void* d_ws, size_t ws_size,
                              hipStream_t stream) {
    const float* x    = (const float*)d_in[0];
    const int*   src  = (const int*)d_in[1];
    const int*   dst  = ((const int*)d_in[1]) + N_EDGES;
    const int*   batch= (const int*)d_in[2];
    const float* W1l  = (const float*)d_in[3];
    const float* b1   = (const float*)d_in[4];
    const float* W1r  = (const float*)d_in[5];
    const float* W2l  = (const float*)d_in[6];
    const float* b2   = (const float*)d_in[7];
    const float* W2r  = (const float*)d_in[8];
    const float* Wlin = (const float*)d_in[9];
    const float* blin = (const float*)d_in[10];
    float* out = (float*)d_out;

    __half* xh     = (__half*)d_ws;                 // 6,400,000 h
    __half* mean16 = xh + 6400000;                  // 6,400,000 h
    __half* h1_16  = mean16 + 6400000;              // 6,400,000 h
    __half* Wt1    = h1_16 + 6400000;               // 32,768 h
    __half* Wt2    = Wt1 + 32768;                   // 32,768 h
    float* invdeg  = (float*)(Wt2 + 32768);         // 50,000 f
    int*   gstart  = (int*)(invdeg + N_NODES);      // 65 i
    // contiguous zero region: pooled, degi, bsum
    float* pooled  = (float*)(gstart + 65);         // 8,192 f
    int*   degi    = (int*)(pooled + N_GRAPHS * 128); // 50,000 i
    int*   bsum    = degi + N_NODES;                // 196 i
    int*   cursor  = bsum + N_SCAN_BLOCKS;          // 50,000 i (init'd by scan)
    int*   rowptr  = cursor + N_NODES;              // 50,001 i
    int*   eidx    = rowptr + N_NODES + 1;          // 600,000 i

    // 1) prep: zero {pooled,degi,bsum} + casts + graph boundaries
    prep_kernel<<<16 + (N_NODES * 128 / 4 + 255) / 256, 256, 0, stream>>>(
        x, batch, W1l, W1r, W2l, W2r, xh, Wt1, Wt2, (int*)pooled, gstart);

    // 2-4) CSR: degrees -> fused lookback scan (inits cursor) -> fill
    deg_kernel<<<(N_EDGES + 255) / 256, 256, 0, stream>>>(dst, degi, N_EDGES);
    scan_fused<<<N_SCAN_BLOCKS, 256, 0, stream>>>(degi, bsum, rowptr, cursor, invdeg);
    fill_kernel<<<(N_EDGES + 255) / 256, 256, 0, stream>>>(src, dst, cursor, eidx, N_EDGES);

    const int gemm_grid = (N_NODES + GBM * MTILES - 1) / (GBM * MTILES);   // 391
    const int agg_grid = (N_NODES + 15) / 16;                              // 3125

    // 5-6) layer 1: gather -> GEMM (stores h1 fp16)
    aggregate_f16<<<agg_grid, 256, 0, stream>>>(xh, rowptr, eidx, invdeg, mean16);
    sage_gemm_f16<<<gemm_grid, 256, 0, stream>>>(mean16, xh, Wt1, b1, batch,
                                                 h1_16, (float*)nullptr, N_NODES);

    // 7-8) layer 2: gather -> GEMM with fused pooling (h2 never materialized)
    aggregate_f16<<<agg_grid, 256, 0, stream>>>(h1_16, rowptr, eidx, invdeg, mean16);
    sage_gemm_f16<<<gemm_grid, 256, 0, stream>>>(mean16, h1_16, Wt2, b2, batch,
                                                 (__half*)nullptr, pooled, N_NODES);

    // 9) final linear
    final_kernel<<<N_GRAPHS, 32, 0, stream>>>(pooled, gstart, Wlin, blin, out);
}